// Round 9
// baseline (181.224 us; speedup 1.0000x reference)
//
#include <hip/hip_runtime.h>

#define DI __device__ __forceinline__

typedef float        f32x4 __attribute__((ext_vector_type(4)));
typedef _Float16     f16x8 __attribute__((ext_vector_type(8)));
typedef unsigned int u32x4 __attribute__((ext_vector_type(4)));
typedef unsigned int u32x2 __attribute__((ext_vector_type(2)));

DI unsigned short f2h(float f){
    _Float16 h = (_Float16)f;           // v_cvt_f16_f32, RNE
    return __builtin_bit_cast(unsigned short, h);
}

// ---------- async global->LDS, 16B per lane ----------
DI void gl_lds16(const void* g, void* l){
    __builtin_amdgcn_global_load_lds(
        (const __attribute__((address_space(1))) unsigned int*)g,
        (__attribute__((address_space(3))) unsigned int*)l, 16, 0, 0);
}

// =====================================================================
// K1: fused tiled transpose + f16 convert for BOTH seg and W_kv.
// 1-D grid: gid<6144 -> seg[b][r][c] -> X[b][c][r]; else Wkv -> WT.
// Input streams are read-once -> nontemporal loads.
// =====================================================================
__global__ __launch_bounds__(256) void k_prep(
    const float* __restrict__ seg, const float* __restrict__ Wkv,
    unsigned short* __restrict__ X, unsigned short* __restrict__ WT)
{
    __shared__ float t[64][65];
    const int gid = blockIdx.x;
    const float* in; unsigned short* out;
    int rows, cols, bx, by, bz; long ibs, obs;
    if (gid < 6144){
        bz = gid / 768; int r = gid % 768; by = r / 12; bx = r % 12;
        in = seg; out = X; rows = 4096; cols = 768;
        ibs = (long)4096 * 768; obs = (long)768 * 4096;
    } else {
        int g2 = gid - 6144; by = g2 / 24; bx = g2 % 24; bz = 0;
        in = Wkv; out = WT; rows = 768; cols = 1536; ibs = 0; obs = 0;
    }
    const int r0 = by * 64, c0 = bx * 64;
    const int tid = threadIdx.x;
    const float* ib = in + (long)bz * ibs;

    #pragma unroll
    for (int i = 0; i < 4; ++i){
        int r  = (tid >> 4) + i * 16;
        int cq = (tid & 15) * 4;
        f32x4 v = __builtin_nontemporal_load(
            (const f32x4*)&ib[(long)(r0 + r) * cols + c0 + cq]);
        t[r][cq+0] = v[0]; t[r][cq+1] = v[1]; t[r][cq+2] = v[2]; t[r][cq+3] = v[3];
    }
    __syncthreads();

    const int c  = tid >> 2;
    const int ms = (tid & 3) * 16;
    unsigned hv[8];
    #pragma unroll
    for (int k2 = 0; k2 < 8; ++k2){
        unsigned short ha = f2h(t[ms + 2*k2 + 0][c]);
        unsigned short hb = f2h(t[ms + 2*k2 + 1][c]);
        hv[k2] = (unsigned)ha | ((unsigned)hb << 16);
    }
    long o = (long)bz * obs + (long)(c0 + c) * rows + r0 + ms;
    u32x4 H0 = {hv[0],hv[1],hv[2],hv[3]}, H1 = {hv[4],hv[5],hv[6],hv[7]};
    *(u32x4*)&out[o]     = H0;
    *(u32x4*)&out[o + 8] = H1;
}

// =====================================================================
// shared bt-GEMM machinery: C[i,j] += sum_k A[i,k]*B[j,k]
// LDS tiles 128x64 f16, double-buffered. gload_lds writes LINEAR dest;
// XOR swizzle (colb ^= (row&7)<<4) applied to GLOBAL source (involution);
// frag_ld reads swizzled (rule 21 / m173).
// =====================================================================
DI void stage_lds(const unsigned short* __restrict__ src, long stride,
                  int row0, int k0, unsigned short* tile, int tid)
{
    #pragma unroll
    for (int it = 0; it < 4; ++it){
        int D    = (it * 256 + tid) * 16;                 // dest byte (linear)
        int row  = D >> 7;
        int colb = (D & 127) ^ ((row & 7) << 4);          // inverse-swizzled source col
        const char* g = (const char*)(src + (long)(row0 + row) * stride + k0) + colb;
        gl_lds16(g, (char*)tile + D);
    }
}

DI f16x8 frag_ld(const unsigned short* tile, int row, int kc16)
{
    int logical = (row << 7) + (kc16 << 4);
    int phys    = logical ^ ((row & 7) << 4);
    return *(const f16x8*)((const char*)tile + phys);
}

DI void mfma_tile(const unsigned short* TA, const unsigned short* TB,
                  int wr, int wc, int lane, f32x4 acc[4][4])
{
    #pragma unroll
    for (int ks = 0; ks < 2; ++ks){
        const int kc = ks * 4 + (lane >> 4);
        f16x8 bf[4];
        #pragma unroll
        for (int cf = 0; cf < 4; ++cf)
            bf[cf] = frag_ld(TB, wc + cf * 16 + (lane & 15), kc);
        #pragma unroll
        for (int rf = 0; rf < 4; ++rf){
            f16x8 af = frag_ld(TA, wr + rf * 16 + (lane & 15), kc);
            #pragma unroll
            for (int cf = 0; cf < 4; ++cf)
                acc[rf][cf] = __builtin_amdgcn_mfma_f32_16x16x32_f16(af, bf[cf], acc[rf][cf], 0, 0, 0);
        }
    }
}

// =====================================================================
// K2: Gram  G_b = X_b * X_b^T  (symmetric pairs i<=j, split-K=3)
// 1-D grid 504 x 256 thr; b = id&7 keeps each batch's panels on one XCD.
// Diagonal blocks (ti==tj) stage one tile and read it as both A and B.
// Writes f16 partials Gp16[ksl][b][768][768].
// =====================================================================
__global__ __launch_bounds__(256) void k_gram(
    const unsigned short* __restrict__ X, unsigned short* __restrict__ Gp16)
{
    __shared__ unsigned short lds[4 * 8192];   // 2 bufs x (A,B) x 16KB
    const int id  = blockIdx.x;
    const int b   = id & 7;
    const int r   = id >> 3;          // 0..62
    const int ksl = r / 21;
    int q = r % 21;
    int ti = 0, tj = 0;
    #pragma unroll
    for (int i = 0; i < 6; ++i){ int c = 6 - i; if (q < c){ ti = i; tj = i + q; q = -1; break; } q -= c; }

    static const int kb[4] = {0, 1408, 2752, 4096};
    const int kbeg = kb[ksl], kend = kb[ksl + 1];

    const unsigned short* XB = X + (long)b * 768 * 4096;
    const int tid  = threadIdx.x;
    const int lane = tid & 63, wave = tid >> 6;
    const int wr = (wave >> 1) * 64, wc = (wave & 1) * 64;
    const bool diag = (ti == tj);

    f32x4 acc[4][4];
    #pragma unroll
    for (int i = 0; i < 4; ++i)
        #pragma unroll
        for (int j = 0; j < 4; ++j) acc[i][j] = (f32x4){0.f, 0.f, 0.f, 0.f};

    stage_lds(XB, 4096, ti * 128, kbeg, lds, tid);
    if (!diag) stage_lds(XB, 4096, tj * 128, kbeg, lds + 8192, tid);
    __syncthreads();

    int cur = 0;
    for (int k0 = kbeg; k0 < kend; k0 += 64){
        const unsigned short* TA = lds + cur * 16384;
        const unsigned short* TB = diag ? TA : TA + 8192;
        const int kn = k0 + 64;
        if (kn < kend){
            unsigned short* NA = lds + (cur ^ 1) * 16384;
            stage_lds(XB, 4096, ti * 128, kn, NA, tid);
            if (!diag) stage_lds(XB, 4096, tj * 128, kn, NA + 8192, tid);
        }
        mfma_tile(TA, TB, wr, wc, lane, acc);
        __syncthreads();   // drains next-tile vmcnt + this tile's lgkm
        cur ^= 1;
    }

    unsigned short* G = Gp16 + ((long)ksl * 8 + b) * 768 * 768;
    #pragma unroll
    for (int rf = 0; rf < 4; ++rf)
        #pragma unroll
        for (int cf = 0; cf < 4; ++cf){
            int gi = ti * 128 + wr + rf * 16 + 4 * (lane >> 4);
            int gj = tj * 128 + wc + cf * 16 + (lane & 15);
            unsigned short h4[4];
            #pragma unroll
            for (int r2 = 0; r2 < 4; ++r2){
                h4[r2] = f2h(acc[rf][cf][r2]);
                G[(long)(gi + r2) * 768 + gj] = h4[r2];
            }
            if (ti != tj){
                // transposed dual-write: gi multiple of 4 -> aligned 8B store
                u32x2 p = { (unsigned)h4[0] | ((unsigned)h4[1] << 16),
                            (unsigned)h4[2] | ((unsigned)h4[3] << 16) };
                *(u32x2*)(G + (long)gj * 768 + gi) = p;
            }
        }
}

// =====================================================================
// K4: TT_b[eg,c] = sum_c' WvT[eg,c'] * (Gp0+Gp1+Gp2)_b[c,c']
// B staged from 3 f16 partials: loads issued BEFORE MFMA, summed+written
// after (T14). 1-D grid 288 x 256 thr; b = id&7 keeps Gp16_b L2-resident.
// =====================================================================
DI void ldB3(const unsigned short* __restrict__ g0, long S16, long stride,
             int row0, int k0, int tid, f16x8 r0[4], f16x8 r1[4], f16x8 r2[4])
{
    #pragma unroll
    for (int it = 0; it < 4; ++it){
        int D    = (it * 256 + tid) * 16;
        int row  = D >> 7;
        int colb = D & 127;
        long off = (long)(row0 + row) * stride + k0 + (colb >> 1);
        r0[it] = *(const f16x8*)(g0 + off);
        r1[it] = *(const f16x8*)(g0 + S16 + off);
        r2[it] = *(const f16x8*)(g0 + 2 * S16 + off);
    }
}
DI void wrB3(unsigned short* tile, int tid, f16x8 r0[4], f16x8 r1[4], f16x8 r2[4])
{
    #pragma unroll
    for (int it = 0; it < 4; ++it){
        int D    = (it * 256 + tid) * 16;
        int row  = D >> 7;
        int colb = D & 127;
        f16x8 s;
        #pragma unroll
        for (int t = 0; t < 8; ++t)
            s[t] = (_Float16)((float)r0[it][t] + (float)r1[it][t] + (float)r2[it][t]);
        int phys = (D & ~127) | (colb ^ ((row & 7) << 4));   // swizzled dest (pairs with frag_ld)
        *(f16x8*)((char*)tile + phys) = s;
    }
}

__global__ __launch_bounds__(256) void k_tt(
    const unsigned short* __restrict__ WT, const unsigned short* __restrict__ Gp16,
    unsigned short* __restrict__ TT)
{
    __shared__ unsigned short lds[4 * 8192];
    const long S16 = 4718592;   // 8*768*768
    const int id = blockIdx.x;
    const int b  = id & 7;
    const int t  = id >> 3;
    const int ti = t % 6, tj = t / 6;
    const int tid = threadIdx.x;

    const unsigned short* A  = WT + (long)768 * 768;     // WvT rows
    const unsigned short* G0 = Gp16 + (long)b * 768 * 768;

    f32x4 acc[4][4];
    #pragma unroll
    for (int i = 0; i < 4; ++i)
        #pragma unroll
        for (int j = 0; j < 4; ++j) acc[i][j] = (f32x4){0.f, 0.f, 0.f, 0.f};

    const int lane = tid & 63;
    const int wave = tid >> 6;
    const int wr = (wave >> 1) * 64, wc = (wave & 1) * 64;

    // prologue: first K-tile
    {
        f16x8 r0[4], r1[4], r2[4];
        ldB3(G0, S16, 768, tj * 128, 0, tid, r0, r1, r2);
        stage_lds(A, 768, ti * 128, 0, lds, tid);
        wrB3(lds + 8192, tid, r0, r1, r2);
        __syncthreads();
    }

    int cur = 0;
    for (int k0 = 0; k0 < 768; k0 += 64){
        const unsigned short* TA = lds + cur * 16384;
        const int kn = k0 + 64;
        f16x8 r0[4], r1[4], r2[4];
        if (kn < 768){
            ldB3(G0, S16, 768, tj * 128, kn, tid, r0, r1, r2);   // loads fly under MFMA
            stage_lds(A, 768, ti * 128, kn, lds + (cur ^ 1) * 16384, tid);
        }
        mfma_tile(TA, TA + 8192, wr, wc, lane, acc);
        if (kn < 768)
            wrB3(lds + (cur ^ 1) * 16384 + 8192, tid, r0, r1, r2);  // vmcnt-wait lands here
        __syncthreads();
        cur ^= 1;
    }

    unsigned short* tt = TT + (long)b * 768 * 768;
    #pragma unroll
    for (int rf = 0; rf < 4; ++rf)
        #pragma unroll
        for (int cf = 0; cf < 4; ++cf){
            int gi = ti * 128 + wr + rf * 16 + 4 * (lane >> 4);
            int gj = tj * 128 + wc + cf * 16 + (lane & 15);
            #pragma unroll
            for (int r = 0; r < 4; ++r)
                tt[(long)(gi + r) * 768 + gj] = f2h(acc[rf][cf][r]);
        }
}

// =====================================================================
// K5: ctx_h = scale * WkT_h ·bt· TT_h  + softmax over d -> wT[e][d] f16
// 4 waves per (b,h): waves split K, LDS-reduce, wave 0 does softmax.
// =====================================================================
__global__ __launch_bounds__(256) void k_ctx(
    const unsigned short* __restrict__ WT, const unsigned short* __restrict__ TT,
    unsigned short* __restrict__ wT)
{
    __shared__ float red[3][64][65];
    const int bh = blockIdx.x;
    const int b = bh / 12, h = bh % 12;
    const int lane = threadIdx.x & 63;
    const int wave = threadIdx.x >> 6;

    const unsigned short* A = WT + (long)(h * 64) * 768;
    const unsigned short* B = TT + (long)b * 768 * 768 + (long)(h * 64) * 768;

    f32x4 acc[4][4];
    #pragma unroll
    for (int i = 0; i < 4; ++i)
        #pragma unroll
        for (int j = 0; j < 4; ++j) acc[i][j] = (f32x4){0.f, 0.f, 0.f, 0.f};

    for (int kc = wave * 6; kc < wave * 6 + 6; ++kc){
        const int k0 = kc * 32 + (lane >> 4) * 8;
        f16x8 af[4], bf[4];
        #pragma unroll
        for (int f = 0; f < 4; ++f){
            long ro = (long)(f * 16 + (lane & 15)) * 768 + k0;
            af[f] = *(const f16x8*)(A + ro);
            bf[f] = *(const f16x8*)(B + ro);
        }
        #pragma unroll
        for (int rf = 0; rf < 4; ++rf)
            #pragma unroll
            for (int cf = 0; cf < 4; ++cf)
                acc[rf][cf] = __builtin_amdgcn_mfma_f32_16x16x32_f16(af[rf], bf[cf], acc[rf][cf], 0, 0, 0);
    }

    if (wave > 0){
        #pragma unroll
        for (int rf = 0; rf < 4; ++rf)
            #pragma unroll
            for (int cf = 0; cf < 4; ++cf)
                #pragma unroll
                for (int r = 0; r < 4; ++r)
                    red[wave - 1][lane][(rf * 4 + cf) * 4 + r] = acc[rf][cf][r];
    }
    __syncthreads();
    if (wave != 0) return;

    #pragma unroll
    for (int rf = 0; rf < 4; ++rf)
        #pragma unroll
        for (int cf = 0; cf < 4; ++cf)
            #pragma unroll
            for (int r = 0; r < 4; ++r){
                int idx = (rf * 4 + cf) * 4 + r;
                acc[rf][cf][r] += red[0][lane][idx] + red[1][lane][idx] + red[2][lane][idx];
            }

    // scale + softmax over d (rows); column e lives in lanes {e, e+16, e+32, e+48}
    unsigned short* wout = wT + (long)bh * 4096;
    #pragma unroll
    for (int cf = 0; cf < 4; ++cf){
        float pv[16];
        float m = -3.4e38f;
        #pragma unroll
        for (int rf = 0; rf < 4; ++rf)
            #pragma unroll
            for (int r = 0; r < 4; ++r){
                float s = acc[rf][cf][r] * 0.125f;
                pv[rf * 4 + r] = s;
                m = fmaxf(m, s);
            }
        m = fmaxf(m, __shfl_xor(m, 16));
        m = fmaxf(m, __shfl_xor(m, 32));
        float sum = 0.f;
        #pragma unroll
        for (int k = 0; k < 16; ++k){ pv[k] = __expf(pv[k] - m); sum += pv[k]; }
        sum += __shfl_xor(sum, 16);
        sum += __shfl_xor(sum, 32);
        float inv = 1.f / sum;
        int e = cf * 16 + (lane & 15);
        #pragma unroll
        for (int rf = 0; rf < 4; ++rf)
            #pragma unroll
            for (int r = 0; r < 4; ++r){
                int d = rf * 16 + 4 * (lane >> 4) + r;
                wout[e * 64 + d] = f2h(pv[rf * 4 + r] * inv);
            }
    }
}

// =====================================================================
// K6: apply — o[src][b][n][h*64+e] = sum_d x[b][n][h*64+d] * w[b,h][e][d]
// Streaming: nontemporal loads (x read-once) + nontemporal stores.
// Epilogue restage split into two wave-local half-passes -> 32 KB LDS
// -> 5 blocks/CU (was 2) for better HBM-pipe TLP.
// =====================================================================
__global__ __launch_bounds__(256) void k_apply(
    const float* __restrict__ x1, const float* __restrict__ x2,
    const unsigned short* __restrict__ wT, float* __restrict__ out)
{
    __shared__ float ep[4][32][64];
    const int b = blockIdx.z;
    const int h = blockIdx.y >> 1;
    const int src = blockIdx.y & 1;
    const int lane = threadIdx.x & 63, wave = threadIdx.x >> 6;
    const int n0 = blockIdx.x * 256 + wave * 64;

    const float* x = (src ? x2 : x1) + (long)b * 4096 * 768;
    float* o = out + (long)src * 8 * 4096 * 768 + (long)b * 4096 * 768;

    const unsigned short* W = wT + (long)(b * 12 + h) * 4096;
    f16x8 bw[4][2];
    #pragma unroll
    for (int fe = 0; fe < 4; ++fe)
        #pragma unroll
        for (int ks = 0; ks < 2; ++ks)
            bw[fe][ks] = *(const f16x8*)(W + (fe * 16 + (lane & 15)) * 64 + ks * 32 + (lane >> 4) * 8);

    f32x4 acc[4][4];
    #pragma unroll
    for (int i = 0; i < 4; ++i)
        #pragma unroll
        for (int j = 0; j < 4; ++j) acc[i][j] = (f32x4){0.f, 0.f, 0.f, 0.f};

    #pragma unroll
    for (int rf = 0; rf < 4; ++rf){
        const int row = n0 + rf * 16 + (lane & 15);
        const float* xr = x + (long)row * 768 + h * 64 + (lane >> 4) * 8;
        f32x4 v0 = __builtin_nontemporal_load((const f32x4*)(xr));
        f32x4 v1 = __builtin_nontemporal_load((const f32x4*)(xr + 4));
        f32x4 v2 = __builtin_nontemporal_load((const f32x4*)(xr + 32));
        f32x4 v3 = __builtin_nontemporal_load((const f32x4*)(xr + 36));
        f16x8 a0, a1;
        #pragma unroll
        for (int t = 0; t < 4; ++t){
            a0[t]     = (_Float16)v0[t];
            a0[t + 4] = (_Float16)v1[t];
            a1[t]     = (_Float16)v2[t];
            a1[t + 4] = (_Float16)v3[t];
        }
        #pragma unroll
        for (int fe = 0; fe < 4; ++fe){
            acc[rf][fe] = __builtin_amdgcn_mfma_f32_16x16x32_f16(a0, bw[fe][0], acc[rf][fe], 0, 0, 0);
            acc[rf][fe] = __builtin_amdgcn_mfma_f32_16x16x32_f16(a1, bw[fe][1], acc[rf][fe], 0, 0, 0);
        }
    }

    // wave-local LDS restage in two half-passes (rows 0-31, 32-63)
    #pragma unroll
    for (int half = 0; half < 2; ++half){
        #pragma unroll
        for (int rf = 0; rf < 2; ++rf)
            #pragma unroll
            for (int fe = 0; fe < 4; ++fe)
                #pragma unroll
                for (int r = 0; r < 4; ++r)
                    ep[wave][rf * 16 + 4 * (lane >> 4) + r][fe * 16 + (lane & 15)]
                        = acc[half * 2 + rf][fe][r];

        #pragma unroll
        for (int pass = 0; pass < 8; ++pass){
            int rr = pass * 4 + (lane >> 4);
            f32x4 v = *(const f32x4*)&ep[wave][rr][(lane & 15) * 4];
            __builtin_nontemporal_store(v,
                (f32x4*)&o[(long)(n0 + half * 32 + rr) * 768 + h * 64 + (lane & 15) * 4]);
        }
    }
}

__global__ void k_sentinel(float* o){ o[0] = 1.0e9f; }

// =====================================================================
extern "C" void kernel_launch(void* const* d_in, const int* in_sizes, int n_in,
                              void* d_out, int out_size, void* d_ws, size_t ws_size,
                              hipStream_t stream)
{
    (void)in_sizes; (void)n_in; (void)out_size;
    const float* x1  = (const float*)d_in[0];
    const float* x2  = (const float*)d_in[1];
    const float* seg = (const float*)d_in[2];
    const float* Wkv = (const float*)d_in[3];

    char* Wb = (char*)d_ws;
    unsigned short* X    = (unsigned short*)(Wb);                 // 50,331,648
    unsigned short* WT   = (unsigned short*)(Wb + 50331648);      //  2,359,296
    unsigned short* TT   = (unsigned short*)(Wb + 52690944);      //  9,437,184
    unsigned short* wT   = (unsigned short*)(Wb + 62128128);      //    786,432
    unsigned short* Gp16 = (unsigned short*)(Wb + 62914560);      // 28,311,552
    const size_t need = 91226112;

    if (ws_size < need){
        k_sentinel<<<1, 1, 0, stream>>>((float*)d_out);
        return;
    }

    // K1: fused transpose+convert for seg and W_kv (one launch)
    k_prep<<<dim3(6432), 256, 0, stream>>>(seg, Wkv, X, WT);

    // K2: Gram, symmetric pairs, split-K=3, XCD-affine, f16 partials, diag-dedup
    k_gram<<<dim3(504), 256, 0, stream>>>(X, Gp16);

    // K4: TT = WvT ·bt· (sum of partials)
    k_tt<<<dim3(288), 256, 0, stream>>>(WT, Gp16, TT);

    // K5: ctx + softmax -> wT
    k_ctx<<<dim3(96), 256, 0, stream>>>(WT, TT, wT);

    // K6: apply to both queries
    k_apply<<<dim3(16, 24, 8), 256, 0, stream>>>(x1, x2, wT, (float*)d_out);
}

// Round 10
// 173.003 us; speedup vs baseline: 1.0475x; 1.0475x over previous
//
#include <hip/hip_runtime.h>

#define DI __device__ __forceinline__

typedef float        f32x4 __attribute__((ext_vector_type(4)));
typedef _Float16     f16x8 __attribute__((ext_vector_type(8)));
typedef unsigned int u32x4 __attribute__((ext_vector_type(4)));
typedef unsigned int u32x2 __attribute__((ext_vector_type(2)));

DI unsigned short f2h(float f){
    _Float16 h = (_Float16)f;           // v_cvt_f16_f32, RNE
    return __builtin_bit_cast(unsigned short, h);
}

// ---------- async global->LDS, 16B per lane ----------
DI void gl_lds16(const void* g, void* l){
    __builtin_amdgcn_global_load_lds(
        (const __attribute__((address_space(1))) unsigned int*)g,
        (__attribute__((address_space(3))) unsigned int*)l, 16, 0, 0);
}

// =====================================================================
// K1: fused tiled transpose + f16 convert for BOTH seg and W_kv.
// 1-D grid: gid<6144 -> seg[b][r][c] -> X[b][c][r]; else Wkv -> WT.
// =====================================================================
__global__ __launch_bounds__(256) void k_prep(
    const float* __restrict__ seg, const float* __restrict__ Wkv,
    unsigned short* __restrict__ X, unsigned short* __restrict__ WT)
{
    __shared__ float t[64][65];
    const int gid = blockIdx.x;
    const float* in; unsigned short* out;
    int rows, cols, bx, by, bz; long ibs, obs;
    if (gid < 6144){
        bz = gid / 768; int r = gid % 768; by = r / 12; bx = r % 12;
        in = seg; out = X; rows = 4096; cols = 768;
        ibs = (long)4096 * 768; obs = (long)768 * 4096;
    } else {
        int g2 = gid - 6144; by = g2 / 24; bx = g2 % 24; bz = 0;
        in = Wkv; out = WT; rows = 768; cols = 1536; ibs = 0; obs = 0;
    }
    const int r0 = by * 64, c0 = bx * 64;
    const int tid = threadIdx.x;
    const float* ib = in + (long)bz * ibs;

    #pragma unroll
    for (int i = 0; i < 4; ++i){
        int r  = (tid >> 4) + i * 16;
        int cq = (tid & 15) * 4;
        f32x4 v = *(const f32x4*)&ib[(long)(r0 + r) * cols + c0 + cq];
        t[r][cq+0] = v[0]; t[r][cq+1] = v[1]; t[r][cq+2] = v[2]; t[r][cq+3] = v[3];
    }
    __syncthreads();

    const int c  = tid >> 2;
    const int ms = (tid & 3) * 16;
    unsigned hv[8];
    #pragma unroll
    for (int k2 = 0; k2 < 8; ++k2){
        unsigned short ha = f2h(t[ms + 2*k2 + 0][c]);
        unsigned short hb = f2h(t[ms + 2*k2 + 1][c]);
        hv[k2] = (unsigned)ha | ((unsigned)hb << 16);
    }
    long o = (long)bz * obs + (long)(c0 + c) * rows + r0 + ms;
    u32x4 H0 = {hv[0],hv[1],hv[2],hv[3]}, H1 = {hv[4],hv[5],hv[6],hv[7]};
    *(u32x4*)&out[o]     = H0;
    *(u32x4*)&out[o + 8] = H1;
}

// =====================================================================
// shared bt-GEMM machinery: C[i,j] += sum_k A[i,k]*B[j,k]
// LDS tiles 128x64 f16, double-buffered. gload_lds writes LINEAR dest;
// XOR swizzle (colb ^= (row&7)<<4) applied to GLOBAL source (involution);
// frag_ld reads swizzled (rule 21 / m173).
// =====================================================================
DI void stage_lds(const unsigned short* __restrict__ src, long stride,
                  int row0, int k0, unsigned short* tile, int tid)
{
    #pragma unroll
    for (int it = 0; it < 4; ++it){
        int D    = (it * 256 + tid) * 16;                 // dest byte (linear)
        int row  = D >> 7;
        int colb = (D & 127) ^ ((row & 7) << 4);          // inverse-swizzled source col
        const char* g = (const char*)(src + (long)(row0 + row) * stride + k0) + colb;
        gl_lds16(g, (char*)tile + D);
    }
}

DI f16x8 frag_ld(const unsigned short* tile, int row, int kc16)
{
    int logical = (row << 7) + (kc16 << 4);
    int phys    = logical ^ ((row & 7) << 4);
    return *(const f16x8*)((const char*)tile + phys);
}

DI void mfma_tile(const unsigned short* TA, const unsigned short* TB,
                  int wr, int wc, int lane, f32x4 acc[4][4])
{
    #pragma unroll
    for (int ks = 0; ks < 2; ++ks){
        const int kc = ks * 4 + (lane >> 4);
        f16x8 bf[4];
        #pragma unroll
        for (int cf = 0; cf < 4; ++cf)
            bf[cf] = frag_ld(TB, wc + cf * 16 + (lane & 15), kc);
        #pragma unroll
        for (int rf = 0; rf < 4; ++rf){
            f16x8 af = frag_ld(TA, wr + rf * 16 + (lane & 15), kc);
            #pragma unroll
            for (int cf = 0; cf < 4; ++cf)
                acc[rf][cf] = __builtin_amdgcn_mfma_f32_16x16x32_f16(af, bf[cf], acc[rf][cf], 0, 0, 0);
        }
    }
}

// =====================================================================
// K2: Gram  G_b = X_b * X_b^T  (symmetric pairs i<=j, split-K=3)
// 1-D grid 504 x 256 thr; b = id&7 keeps each batch's panels on one XCD.
// Diagonal blocks (ti==tj) stage one tile and read it as both A and B.
// Writes f16 partials Gp16[ksl][b][768][768].
// =====================================================================
__global__ __launch_bounds__(256) void k_gram(
    const unsigned short* __restrict__ X, unsigned short* __restrict__ Gp16)
{
    __shared__ unsigned short lds[4 * 8192];   // 2 bufs x (A,B) x 16KB
    const int id  = blockIdx.x;
    const int b   = id & 7;
    const int r   = id >> 3;          // 0..62
    const int ksl = r / 21;
    int q = r % 21;
    int ti = 0, tj = 0;
    #pragma unroll
    for (int i = 0; i < 6; ++i){ int c = 6 - i; if (q < c){ ti = i; tj = i + q; q = -1; break; } q -= c; }

    static const int kb[4] = {0, 1408, 2752, 4096};
    const int kbeg = kb[ksl], kend = kb[ksl + 1];

    const unsigned short* XB = X + (long)b * 768 * 4096;
    const int tid  = threadIdx.x;
    const int lane = tid & 63, wave = tid >> 6;
    const int wr = (wave >> 1) * 64, wc = (wave & 1) * 64;
    const bool diag = (ti == tj);

    f32x4 acc[4][4];
    #pragma unroll
    for (int i = 0; i < 4; ++i)
        #pragma unroll
        for (int j = 0; j < 4; ++j) acc[i][j] = (f32x4){0.f, 0.f, 0.f, 0.f};

    stage_lds(XB, 4096, ti * 128, kbeg, lds, tid);
    if (!diag) stage_lds(XB, 4096, tj * 128, kbeg, lds + 8192, tid);
    __syncthreads();

    int cur = 0;
    for (int k0 = kbeg; k0 < kend; k0 += 64){
        const unsigned short* TA = lds + cur * 16384;
        const unsigned short* TB = diag ? TA : TA + 8192;
        const int kn = k0 + 64;
        if (kn < kend){
            unsigned short* NA = lds + (cur ^ 1) * 16384;
            stage_lds(XB, 4096, ti * 128, kn, NA, tid);
            if (!diag) stage_lds(XB, 4096, tj * 128, kn, NA + 8192, tid);
        }
        mfma_tile(TA, TB, wr, wc, lane, acc);
        __syncthreads();   // drains next-tile vmcnt + this tile's lgkm
        cur ^= 1;
    }

    unsigned short* G = Gp16 + ((long)ksl * 8 + b) * 768 * 768;
    #pragma unroll
    for (int rf = 0; rf < 4; ++rf)
        #pragma unroll
        for (int cf = 0; cf < 4; ++cf){
            int gi = ti * 128 + wr + rf * 16 + 4 * (lane >> 4);
            int gj = tj * 128 + wc + cf * 16 + (lane & 15);
            unsigned short h4[4];
            #pragma unroll
            for (int r2 = 0; r2 < 4; ++r2){
                h4[r2] = f2h(acc[rf][cf][r2]);
                G[(long)(gi + r2) * 768 + gj] = h4[r2];
            }
            if (ti != tj){
                // transposed dual-write: gi multiple of 4 -> aligned 8B store
                u32x2 p = { (unsigned)h4[0] | ((unsigned)h4[1] << 16),
                            (unsigned)h4[2] | ((unsigned)h4[3] << 16) };
                *(u32x2*)(G + (long)gj * 768 + gi) = p;
            }
        }
}

// =====================================================================
// K4: TT_b[eg,c] = sum_c' WvT[eg,c'] * (Gp0+Gp1+Gp2)_b[c,c']
// B staged from 3 f16 partials: loads issued BEFORE MFMA, summed+written
// after (T14). 1-D grid 288 x 256 thr; b = id&7 keeps Gp16_b L2-resident.
// =====================================================================
DI void ldB3(const unsigned short* __restrict__ g0, long S16, long stride,
             int row0, int k0, int tid, f16x8 r0[4], f16x8 r1[4], f16x8 r2[4])
{
    #pragma unroll
    for (int it = 0; it < 4; ++it){
        int D    = (it * 256 + tid) * 16;
        int row  = D >> 7;
        int colb = D & 127;
        long off = (long)(row0 + row) * stride + k0 + (colb >> 1);
        r0[it] = *(const f16x8*)(g0 + off);
        r1[it] = *(const f16x8*)(g0 + S16 + off);
        r2[it] = *(const f16x8*)(g0 + 2 * S16 + off);
    }
}
DI void wrB3(unsigned short* tile, int tid, f16x8 r0[4], f16x8 r1[4], f16x8 r2[4])
{
    #pragma unroll
    for (int it = 0; it < 4; ++it){
        int D    = (it * 256 + tid) * 16;
        int row  = D >> 7;
        int colb = D & 127;
        f16x8 s;
        #pragma unroll
        for (int t = 0; t < 8; ++t)
            s[t] = (_Float16)((float)r0[it][t] + (float)r1[it][t] + (float)r2[it][t]);
        int phys = (D & ~127) | (colb ^ ((row & 7) << 4));   // swizzled dest (pairs with frag_ld)
        *(f16x8*)((char*)tile + phys) = s;
    }
}

__global__ __launch_bounds__(256) void k_tt(
    const unsigned short* __restrict__ WT, const unsigned short* __restrict__ Gp16,
    unsigned short* __restrict__ TT)
{
    __shared__ unsigned short lds[4 * 8192];
    const long S16 = 4718592;   // 8*768*768
    const int id = blockIdx.x;
    const int b  = id & 7;
    const int t  = id >> 3;
    const int ti = t % 6, tj = t / 6;
    const int tid = threadIdx.x;

    const unsigned short* A  = WT + (long)768 * 768;     // WvT rows
    const unsigned short* G0 = Gp16 + (long)b * 768 * 768;

    f32x4 acc[4][4];
    #pragma unroll
    for (int i = 0; i < 4; ++i)
        #pragma unroll
        for (int j = 0; j < 4; ++j) acc[i][j] = (f32x4){0.f, 0.f, 0.f, 0.f};

    const int lane = tid & 63;
    const int wave = tid >> 6;
    const int wr = (wave >> 1) * 64, wc = (wave & 1) * 64;

    // prologue: first K-tile
    {
        f16x8 r0[4], r1[4], r2[4];
        ldB3(G0, S16, 768, tj * 128, 0, tid, r0, r1, r2);
        stage_lds(A, 768, ti * 128, 0, lds, tid);
        wrB3(lds + 8192, tid, r0, r1, r2);
        __syncthreads();
    }

    int cur = 0;
    for (int k0 = 0; k0 < 768; k0 += 64){
        const unsigned short* TA = lds + cur * 16384;
        const int kn = k0 + 64;
        f16x8 r0[4], r1[4], r2[4];
        if (kn < 768){
            ldB3(G0, S16, 768, tj * 128, kn, tid, r0, r1, r2);   // loads fly under MFMA
            stage_lds(A, 768, ti * 128, kn, lds + (cur ^ 1) * 16384, tid);
        }
        mfma_tile(TA, TA + 8192, wr, wc, lane, acc);
        if (kn < 768)
            wrB3(lds + (cur ^ 1) * 16384 + 8192, tid, r0, r1, r2);  // vmcnt-wait lands here
        __syncthreads();
        cur ^= 1;
    }

    unsigned short* tt = TT + (long)b * 768 * 768;
    #pragma unroll
    for (int rf = 0; rf < 4; ++rf)
        #pragma unroll
        for (int cf = 0; cf < 4; ++cf){
            int gi = ti * 128 + wr + rf * 16 + 4 * (lane >> 4);
            int gj = tj * 128 + wc + cf * 16 + (lane & 15);
            #pragma unroll
            for (int r = 0; r < 4; ++r)
                tt[(long)(gi + r) * 768 + gj] = f2h(acc[rf][cf][r]);
        }
}

// =====================================================================
// K5: ctx_h = scale * WkT_h ·bt· TT_h  + softmax over d -> wT[e][d] f16
// 4 waves per (b,h): waves split K, LDS-reduce, wave 0 does softmax.
// =====================================================================
__global__ __launch_bounds__(256) void k_ctx(
    const unsigned short* __restrict__ WT, const unsigned short* __restrict__ TT,
    unsigned short* __restrict__ wT)
{
    __shared__ float red[3][64][65];
    const int bh = blockIdx.x;
    const int b = bh / 12, h = bh % 12;
    const int lane = threadIdx.x & 63;
    const int wave = threadIdx.x >> 6;

    const unsigned short* A = WT + (long)(h * 64) * 768;
    const unsigned short* B = TT + (long)b * 768 * 768 + (long)(h * 64) * 768;

    f32x4 acc[4][4];
    #pragma unroll
    for (int i = 0; i < 4; ++i)
        #pragma unroll
        for (int j = 0; j < 4; ++j) acc[i][j] = (f32x4){0.f, 0.f, 0.f, 0.f};

    for (int kc = wave * 6; kc < wave * 6 + 6; ++kc){
        const int k0 = kc * 32 + (lane >> 4) * 8;
        f16x8 af[4], bf[4];
        #pragma unroll
        for (int f = 0; f < 4; ++f){
            long ro = (long)(f * 16 + (lane & 15)) * 768 + k0;
            af[f] = *(const f16x8*)(A + ro);
            bf[f] = *(const f16x8*)(B + ro);
        }
        #pragma unroll
        for (int rf = 0; rf < 4; ++rf)
            #pragma unroll
            for (int cf = 0; cf < 4; ++cf)
                acc[rf][cf] = __builtin_amdgcn_mfma_f32_16x16x32_f16(af[rf], bf[cf], acc[rf][cf], 0, 0, 0);
    }

    if (wave > 0){
        #pragma unroll
        for (int rf = 0; rf < 4; ++rf)
            #pragma unroll
            for (int cf = 0; cf < 4; ++cf)
                #pragma unroll
                for (int r = 0; r < 4; ++r)
                    red[wave - 1][lane][(rf * 4 + cf) * 4 + r] = acc[rf][cf][r];
    }
    __syncthreads();
    if (wave != 0) return;

    #pragma unroll
    for (int rf = 0; rf < 4; ++rf)
        #pragma unroll
        for (int cf = 0; cf < 4; ++cf)
            #pragma unroll
            for (int r = 0; r < 4; ++r){
                int idx = (rf * 4 + cf) * 4 + r;
                acc[rf][cf][r] += red[0][lane][idx] + red[1][lane][idx] + red[2][lane][idx];
            }

    // scale + softmax over d (rows); column e lives in lanes {e, e+16, e+32, e+48}
    unsigned short* wout = wT + (long)bh * 4096;
    #pragma unroll
    for (int cf = 0; cf < 4; ++cf){
        float pv[16];
        float m = -3.4e38f;
        #pragma unroll
        for (int rf = 0; rf < 4; ++rf)
            #pragma unroll
            for (int r = 0; r < 4; ++r){
                float s = acc[rf][cf][r] * 0.125f;
                pv[rf * 4 + r] = s;
                m = fmaxf(m, s);
            }
        m = fmaxf(m, __shfl_xor(m, 16));
        m = fmaxf(m, __shfl_xor(m, 32));
        float sum = 0.f;
        #pragma unroll
        for (int k = 0; k < 16; ++k){ pv[k] = __expf(pv[k] - m); sum += pv[k]; }
        sum += __shfl_xor(sum, 16);
        sum += __shfl_xor(sum, 32);
        float inv = 1.f / sum;
        int e = cf * 16 + (lane & 15);
        #pragma unroll
        for (int rf = 0; rf < 4; ++rf)
            #pragma unroll
            for (int r = 0; r < 4; ++r){
                int d = rf * 16 + 4 * (lane >> 4) + r;
                wout[e * 64 + d] = f2h(pv[rf * 4 + r] * inv);
            }
    }
}

// =====================================================================
// K6: apply — o[src][b][n][h*64+e] = sum_d x[b][n][h*64+d] * w[b,h][e][d]
// Output stores nontemporal (write-once 201 MB; don't displace L2 sets).
// =====================================================================
__global__ __launch_bounds__(256) void k_apply(
    const float* __restrict__ x1, const float* __restrict__ x2,
    const unsigned short* __restrict__ wT, float* __restrict__ out)
{
    __shared__ float ep[4][64][64];
    const int b = blockIdx.z;
    const int h = blockIdx.y >> 1;
    const int src = blockIdx.y & 1;
    const int lane = threadIdx.x & 63, wave = threadIdx.x >> 6;
    const int n0 = blockIdx.x * 256 + wave * 64;

    const float* x = (src ? x2 : x1) + (long)b * 4096 * 768;
    float* o = out + (long)src * 8 * 4096 * 768 + (long)b * 4096 * 768;

    const unsigned short* W = wT + (long)(b * 12 + h) * 4096;
    f16x8 bw[4][2];
    #pragma unroll
    for (int fe = 0; fe < 4; ++fe)
        #pragma unroll
        for (int ks = 0; ks < 2; ++ks)
            bw[fe][ks] = *(const f16x8*)(W + (fe * 16 + (lane & 15)) * 64 + ks * 32 + (lane >> 4) * 8);

    f32x4 acc[4][4];
    #pragma unroll
    for (int i = 0; i < 4; ++i)
        #pragma unroll
        for (int j = 0; j < 4; ++j) acc[i][j] = (f32x4){0.f, 0.f, 0.f, 0.f};

    #pragma unroll
    for (int rf = 0; rf < 4; ++rf){
        const int row = n0 + rf * 16 + (lane & 15);
        const float* xr = x + (long)row * 768 + h * 64 + (lane >> 4) * 8;
        f32x4 v0 = *(const f32x4*)(xr);
        f32x4 v1 = *(const f32x4*)(xr + 4);
        f32x4 v2 = *(const f32x4*)(xr + 32);
        f32x4 v3 = *(const f32x4*)(xr + 36);
        f16x8 a0, a1;
        #pragma unroll
        for (int t = 0; t < 4; ++t){
            a0[t]     = (_Float16)v0[t];
            a0[t + 4] = (_Float16)v1[t];
            a1[t]     = (_Float16)v2[t];
            a1[t + 4] = (_Float16)v3[t];
        }
        #pragma unroll
        for (int fe = 0; fe < 4; ++fe){
            acc[rf][fe] = __builtin_amdgcn_mfma_f32_16x16x32_f16(a0, bw[fe][0], acc[rf][fe], 0, 0, 0);
            acc[rf][fe] = __builtin_amdgcn_mfma_f32_16x16x32_f16(a1, bw[fe][1], acc[rf][fe], 0, 0, 0);
        }
    }

    // wave-local LDS restage for coalesced float4 stores
    #pragma unroll
    for (int rf = 0; rf < 4; ++rf)
        #pragma unroll
        for (int fe = 0; fe < 4; ++fe)
            #pragma unroll
            for (int r = 0; r < 4; ++r)
                ep[wave][rf * 16 + 4 * (lane >> 4) + r][fe * 16 + (lane & 15)] = acc[rf][fe][r];

    #pragma unroll
    for (int pass = 0; pass < 16; ++pass){
        int rr = pass * 4 + (lane >> 4);
        f32x4 v = *(const f32x4*)&ep[wave][rr][(lane & 15) * 4];
        __builtin_nontemporal_store(v, (f32x4*)&o[(long)(n0 + rr) * 768 + h * 64 + (lane & 15) * 4]);
    }
}

__global__ void k_sentinel(float* o){ o[0] = 1.0e9f; }

// =====================================================================
extern "C" void kernel_launch(void* const* d_in, const int* in_sizes, int n_in,
                              void* d_out, int out_size, void* d_ws, size_t ws_size,
                              hipStream_t stream)
{
    (void)in_sizes; (void)n_in; (void)out_size;
    const float* x1  = (const float*)d_in[0];
    const float* x2  = (const float*)d_in[1];
    const float* seg = (const float*)d_in[2];
    const float* Wkv = (const float*)d_in[3];

    char* Wb = (char*)d_ws;
    unsigned short* X    = (unsigned short*)(Wb);                 // 50,331,648
    unsigned short* WT   = (unsigned short*)(Wb + 50331648);      //  2,359,296
    unsigned short* TT   = (unsigned short*)(Wb + 52690944);      //  9,437,184
    unsigned short* wT   = (unsigned short*)(Wb + 62128128);      //    786,432
    unsigned short* Gp16 = (unsigned short*)(Wb + 62914560);      // 28,311,552
    const size_t need = 91226112;

    if (ws_size < need){
        k_sentinel<<<1, 1, 0, stream>>>((float*)d_out);
        return;
    }

    // K1: fused transpose+convert for seg and W_kv (one launch)
    k_prep<<<dim3(6432), 256, 0, stream>>>(seg, Wkv, X, WT);

    // K2: Gram, symmetric pairs, split-K=3, XCD-affine, f16 partials, diag-dedup
    k_gram<<<dim3(504), 256, 0, stream>>>(X, Gp16);

    // K4: TT = WvT ·bt· (sum of partials)
    k_tt<<<dim3(288), 256, 0, stream>>>(WT, Gp16, TT);

    // K5: ctx + softmax -> wT
    k_ctx<<<dim3(96), 256, 0, stream>>>(WT, TT, wT);

    // K6: apply to both queries
    k_apply<<<dim3(16, 24, 8), 256, 0, stream>>>(x1, x2, wT, (float*)d_out);
}